// Round 4
// baseline (434.530 us; speedup 1.0000x reference)
//
#include <hip/hip_runtime.h>
#include <math.h>

#define SEQ 512
#define HID 768
#define NBATCH 16
#define ROWS 8192
#define INV_SQRT_D 0.07216878364870323f

typedef short s8v __attribute__((ext_vector_type(8)));
typedef float f4v __attribute__((ext_vector_type(4)));
typedef unsigned short u16;

// ---- bf16 helpers (RNE) ----
__device__ __forceinline__ u16 f2bf(float f) {
  unsigned u = __builtin_bit_cast(unsigned, f);
  unsigned r = u + 0x7FFFu + ((u >> 16) & 1u);
  return (u16)(r >> 16);
}
__device__ __forceinline__ float bf2f(u16 s) {
  unsigned u = ((unsigned)s) << 16;
  return __builtin_bit_cast(float, u);
}

// async global->LDS, 16B per lane; lds dest is wave-uniform base + lane*16
__device__ __forceinline__ void gl2lds16(const u16* g, u16* l) {
  __builtin_amdgcn_global_load_lds((const __attribute__((address_space(1))) void*)g,
                                   (__attribute__((address_space(3))) void*)l, 16, 0, 0);
}

// ---------------------------------------------------------------------------
// Swizzled LDS tile layout (BK=32): logical (row, chunk=k>>3) stored at
// row*32 + ((chunk + (row>>1))&3)*8  -> conflict-free b128 frag reads AND
// coalesced staging (4-lane groups read a permutation of one 64B segment).
// ---------------------------------------------------------------------------
template <int KSTEPS>
__device__ __forceinline__ void mm_core128(
    const u16* __restrict__ Ah, const u16* __restrict__ Al, const int lda,
    const u16* __restrict__ Bh, const u16* __restrict__ Bl, const int ldb,
    u16* lds, f4v (&acc)[4][4])
{
  const int tid = threadIdx.x;
  const int w = tid >> 6, ln = tid & 63;
  const u16* src; int ld;
  if (w == 0)      { src = Ah; ld = lda; }
  else if (w == 1) { src = Al; ld = lda; }
  else if (w == 2) { src = Bh; ld = ldb; }
  else             { src = Bl; ld = ldb; }
  u16* myTile = lds + w * 4096;
  const int srow = ln >> 2;
  const int csw  = ((ln & 3) - (ln >> 3)) & 3;
  const int ml = ln & 15, quad = ln >> 4;
  const int fo2 = (((ln >> 4) + ((ln >> 1) & 3)) & 3) * 8;
  const int wr = (w >> 1) * 64, wc = (w & 1) * 64;

  for (int ks = 0; ks < KSTEPS; ++ks) {
    const int k0 = ks * 32;
    const u16* sb = src + (size_t)srow * ld + k0 + csw * 8;
#pragma unroll
    for (int t = 0; t < 8; ++t)
      gl2lds16(sb + (size_t)(t * 16) * ld, myTile + t * 512);
    __syncthreads();
    s8v ah[4], al[4], bh[4], bl[4];
#pragma unroll
    for (int i = 0; i < 4; ++i) {
      const int ra = (wr + i * 16 + ml) * 32 + fo2;
      ah[i] = *(const s8v*)&lds[ra];
      al[i] = *(const s8v*)&lds[4096 + ra];
      const int rb = (wc + i * 16 + ml) * 32 + fo2;
      bh[i] = *(const s8v*)&lds[8192 + rb];
      bl[i] = *(const s8v*)&lds[12288 + rb];
    }
#pragma unroll
    for (int i = 0; i < 4; ++i)
#pragma unroll
      for (int j = 0; j < 4; ++j)
        acc[i][j] = __builtin_amdgcn_mfma_f32_16x16x32_bf16(ah[i], bh[j], acc[i][j], 0, 0, 0);
#pragma unroll
    for (int i = 0; i < 4; ++i)
#pragma unroll
      for (int j = 0; j < 4; ++j)
        acc[i][j] = __builtin_amdgcn_mfma_f32_16x16x32_bf16(ah[i], bl[j], acc[i][j], 0, 0, 0);
#pragma unroll
    for (int i = 0; i < 4; ++i)
#pragma unroll
      for (int j = 0; j < 4; ++j)
        acc[i][j] = __builtin_amdgcn_mfma_f32_16x16x32_bf16(al[i], bh[j], acc[i][j], 0, 0, 0);
    __syncthreads();
  }
}

// ---- prep: split x into hi/lo bf16 ----
__global__ __launch_bounds__(256) void splitx(const float* __restrict__ x,
                                              u16* __restrict__ xh, u16* __restrict__ xl)
{
  const int i = blockIdx.x * 256 + threadIdx.x;
  const float4 v = ((const float4*)x)[i];
  u16 h0 = f2bf(v.x), h1 = f2bf(v.y), h2 = f2bf(v.z), h3 = f2bf(v.w);
  ushort4 hv = make_ushort4(h0, h1, h2, h3);
  ushort4 lv = make_ushort4(f2bf(v.x - bf2f(h0)), f2bf(v.y - bf2f(h1)),
                            f2bf(v.z - bf2f(h2)), f2bf(v.w - bf2f(h3)));
  ((ushort4*)xh)[i] = hv;
  ((ushort4*)xl)[i] = lv;
}

// ---- prep: transpose + split weights: WT[z][n][k] = W_z[k][n] ----
__global__ __launch_bounds__(256) void wsplit(
    const float* __restrict__ Wq, const float* __restrict__ Wk,
    const float* __restrict__ Wv, const float* __restrict__ Wo,
    u16* __restrict__ WTh, u16* __restrict__ WTl)
{
  __shared__ float t[32][33];
  const int z = blockIdx.z;
  const float* W = (z == 0) ? Wq : (z == 1) ? Wk : (z == 2) ? Wv : Wo;
  const int n0 = blockIdx.x * 32, k0 = blockIdx.y * 32;
  const int tx = threadIdx.x & 31, ty = threadIdx.x >> 5;
#pragma unroll
  for (int i = 0; i < 4; ++i)
    t[ty + 8 * i][tx] = W[(size_t)(k0 + ty + 8 * i) * HID + n0 + tx];
  __syncthreads();
#pragma unroll
  for (int i = 0; i < 4; ++i) {
    const float v = t[tx][ty + 8 * i];
    const size_t idx = (size_t)z * HID * HID + (size_t)(n0 + ty + 8 * i) * HID + k0 + tx;
    const u16 hi = f2bf(v);
    WTh[idx] = hi;
    WTl[idx] = f2bf(v - bf2f(hi));
  }
}

// ---------------------------------------------------------------------------
// Fused QKV: one block = 128(M) x 64(N) tile of q, k AND v from one A-tile.
// LDS per K-step: Ah,Al (128x32 each) + 3x{Bh,Bl} (64x32 each) = 40KB.
// Per wave per barrier: 72 MFMA (~350cyc) vs 20 ds_read_b128 (~240cyc).
// Staging: 2560 16B-chunks/step, 10 per thread, pointers precomputed.
// ---------------------------------------------------------------------------
__global__ __launch_bounds__(256) void qkv_fused(
    const u16* __restrict__ xh, const u16* __restrict__ xl,
    const u16* __restrict__ WTh, const u16* __restrict__ WTl,
    const float* __restrict__ bq, const float* __restrict__ bk, const float* __restrict__ bv,
    u16* __restrict__ qh, u16* __restrict__ ql,
    u16* __restrict__ kh, u16* __restrict__ kl, float* __restrict__ vtmp)
{
  __shared__ u16 lds[20480];       // A:[0,8192) u16, B z: 8192+z*4096 (+2048 lo)
  const int tid = threadIdx.x;
  const int w = tid >> 6, ln = tid & 63;
  const int bm = blockIdx.y * 128;
  const int bn = blockIdx.x * 64;
  const int ml = ln & 15, quad = ln >> 4;
  const int fo2 = ((quad + (ml >> 1)) & 3) * 8;
  const int wr = (w >> 1) * 64, wc = (w & 1) * 32;

  // precompute 10 staging source pointers (loop-invariant part)
  const u16* srcs[10];
#pragma unroll
  for (int i = 0; i < 10; ++i) {
    const int C = (w * 10 + i) * 64 + ln;       // global chunk id, 0..2559
    const u16* s;
    if (C < 1024) {                             // A region (Ah then Al)
      const int t = C & 511;
      const int r = t >> 2, sc = t & 3;
      const int lc = (sc - (r >> 1)) & 3;
      const u16* base = (C >> 9) ? xl : xh;
      s = base + (size_t)(bm + r) * HID + lc * 8;
    } else {                                    // B region: z-major, hi then lo
      const int D = C - 1024;
      const int z = D >> 9;
      const int e = D & 511;
      const int t = e & 255;
      const int r = t >> 2, sc = t & 3;
      const int lc = (sc - (r >> 1)) & 3;
      const u16* base = (e >> 8) ? WTl : WTh;
      s = base + (size_t)z * HID * HID + (size_t)(bn + r) * HID + lc * 8;
    }
    srcs[i] = s;
  }

  f4v acc[3][4][2];
#pragma unroll
  for (int z = 0; z < 3; ++z)
#pragma unroll
    for (int i = 0; i < 4; ++i)
#pragma unroll
      for (int j = 0; j < 2; ++j) acc[z][i][j] = (f4v)0.f;

  for (int ks = 0; ks < 24; ++ks) {
#pragma unroll
    for (int i = 0; i < 10; ++i)
      gl2lds16(srcs[i] + ks * 32, lds + (w * 10 + i) * 512);
    __syncthreads();
    s8v ah[4], al[4];
#pragma unroll
    for (int i = 0; i < 4; ++i) {
      const int ra = (wr + i * 16 + ml) * 32 + fo2;
      ah[i] = *(const s8v*)&lds[ra];
      al[i] = *(const s8v*)&lds[4096 + ra];
    }
#pragma unroll
    for (int z = 0; z < 3; ++z) {
      s8v bh[2], bl[2];
#pragma unroll
      for (int j = 0; j < 2; ++j) {
        const int rb = (wc + j * 16 + ml) * 32 + fo2;
        bh[j] = *(const s8v*)&lds[8192 + z * 4096 + rb];
        bl[j] = *(const s8v*)&lds[8192 + z * 4096 + 2048 + rb];
      }
#pragma unroll
      for (int i = 0; i < 4; ++i)
#pragma unroll
        for (int j = 0; j < 2; ++j) {
          acc[z][i][j] = __builtin_amdgcn_mfma_f32_16x16x32_bf16(ah[i], bh[j], acc[z][i][j], 0, 0, 0);
          acc[z][i][j] = __builtin_amdgcn_mfma_f32_16x16x32_bf16(ah[i], bl[j], acc[z][i][j], 0, 0, 0);
          acc[z][i][j] = __builtin_amdgcn_mfma_f32_16x16x32_bf16(al[i], bh[j], acc[z][i][j], 0, 0, 0);
        }
    }
    __syncthreads();
  }

#pragma unroll
  for (int z = 0; z < 3; ++z) {
    const float* bias = (z == 0) ? bq : (z == 1) ? bk : bv;
#pragma unroll
    for (int i = 0; i < 4; ++i)
#pragma unroll
      for (int j = 0; j < 2; ++j) {
        const int gcol = bn + wc + j * 16 + ml;
        const float bv_ = bias[gcol];
#pragma unroll
        for (int r = 0; r < 4; ++r) {
          const int grow = bm + wr + i * 16 + quad * 4 + r;
          const float v = acc[z][i][j][r] + bv_;
          const size_t idx = (size_t)grow * HID + gcol;
          if (z == 2) {
            vtmp[idx] = v;
          } else {
            const u16 hi = f2bf(v);
            const u16 lo = f2bf(v - bf2f(hi));
            if (z == 0) { qh[idx] = hi; ql[idx] = lo; }
            else        { kh[idx] = hi; kl[idx] = lo; }
          }
        }
      }
  }
}

// ---- prep: transpose + split v: vT[b][n][c] = vtmp[b][c][n] ----
__global__ __launch_bounds__(256) void vtrans(const float* __restrict__ vtmp,
                                              u16* __restrict__ vTh, u16* __restrict__ vTl)
{
  __shared__ float t[32][33];
  const int b = blockIdx.z, n0 = blockIdx.x * 32, c0 = blockIdx.y * 32;
  const int tx = threadIdx.x & 31, ty = threadIdx.x >> 5;
  const float* src = vtmp + (size_t)b * SEQ * HID;
#pragma unroll
  for (int i = 0; i < 4; ++i)
    t[ty + 8 * i][tx] = src[(size_t)(c0 + ty + 8 * i) * HID + n0 + tx];
  __syncthreads();
#pragma unroll
  for (int i = 0; i < 4; ++i) {
    const float v = t[tx][ty + 8 * i];
    const size_t idx = (size_t)b * HID * SEQ + (size_t)(n0 + ty + 8 * i) * SEQ + c0 + tx;
    const u16 hi = f2bf(v);
    vTh[idx] = hi;
    vTl[idx] = f2bf(v - bf2f(hi));
  }
}

// ---- scores GEMM + fused rel-bias/scale/dist-mask epilogue (fp32 out) ----
__global__ __launch_bounds__(256) void scores_mm(
    const u16* __restrict__ qh, const u16* __restrict__ ql,
    const u16* __restrict__ kh, const u16* __restrict__ kl, float* __restrict__ sc)
{
  __shared__ u16 lds[16384];
  const int z = blockIdx.z, b = z >> 2, hh = z & 3;
  const int bm = blockIdx.y * 128, bn = blockIdx.x * 128;
  const size_t abase = (size_t)(b * SEQ + bm) * HID + hh * 192;
  const size_t bbase = (size_t)(b * SEQ + bn) * HID + hh * 192;
  f4v acc[4][4];
#pragma unroll
  for (int i = 0; i < 4; ++i)
#pragma unroll
    for (int j = 0; j < 4; ++j) acc[i][j] = (f4v)0.f;
  mm_core128<6>(qh + abase, ql + abase, HID, kh + bbase, kl + bbase, HID, lds, acc);
  const int tid = threadIdx.x, w = tid >> 6, ln = tid & 63;
  const int ml = ln & 15, quad = ln >> 4;
  const int wr = (w >> 1) * 64, wc = (w & 1) * 64;
  float* sch = sc + (size_t)z * SEQ * SEQ;
#pragma unroll
  for (int i = 0; i < 4; ++i)
#pragma unroll
    for (int j = 0; j < 4; ++j) {
      const int scol = bn + wc + j * 16 + ml;
#pragma unroll
      for (int r = 0; r < 4; ++r) {
        const int srow = bm + wr + i * 16 + quad * 4 + r;
        const float dist = fabsf((float)(srow - scol));
        const float rel = __expf(-0.1f * fminf(dist, 5.0f));
        sch[(size_t)srow * SEQ + scol] =
            (acc[i][j][r] + rel) * INV_SQRT_D - 0.1f * dist;
      }
    }
}

// ---- softmax in-place, writes probs hi/lo bf16 into the same row bytes ----
__global__ __launch_bounds__(256) void softmax_split(float* __restrict__ sc)
{
  const int blk = blockIdx.x;
  const int z = blk >> 7, rg = blk & 127;
  const int tid = threadIdx.x;
  const int rr = tid >> 6, lane = tid & 63;
  const int r = rg * 4 + rr;
  float* row = sc + (size_t)z * SEQ * SEQ + (size_t)r * SEQ;
  float4 v0 = *(const float4*)(row + lane * 8);
  float4 v1 = *(const float4*)(row + lane * 8 + 4);
  float mx = fmaxf(fmaxf(fmaxf(v0.x, v0.y), fmaxf(v0.z, v0.w)),
                   fmaxf(fmaxf(v1.x, v1.y), fmaxf(v1.z, v1.w)));
#pragma unroll
  for (int o = 32; o > 0; o >>= 1) mx = fmaxf(mx, __shfl_xor(mx, o, 64));
  v0.x = __expf(v0.x - mx); v0.y = __expf(v0.y - mx);
  v0.z = __expf(v0.z - mx); v0.w = __expf(v0.w - mx);
  v1.x = __expf(v1.x - mx); v1.y = __expf(v1.y - mx);
  v1.z = __expf(v1.z - mx); v1.w = __expf(v1.w - mx);
  float s = v0.x + v0.y + v0.z + v0.w + v1.x + v1.y + v1.z + v1.w;
#pragma unroll
  for (int o = 32; o > 0; o >>= 1) s += __shfl_xor(s, o, 64);
  const float inv = 1.0f / s;
  float p[8] = {v0.x * inv, v0.y * inv, v0.z * inv, v0.w * inv,
                v1.x * inv, v1.y * inv, v1.z * inv, v1.w * inv};
  u16 hi[8], lo[8];
#pragma unroll
  for (int t = 0; t < 8; ++t) {
    hi[t] = f2bf(p[t]);
    lo[t] = f2bf(p[t] - bf2f(hi[t]));
  }
  u16* ph = (u16*)row;
  ushort4* d0 = (ushort4*)&ph[lane * 8];
  d0[0] = make_ushort4(hi[0], hi[1], hi[2], hi[3]);
  d0[1] = make_ushort4(hi[4], hi[5], hi[6], hi[7]);
  ushort4* d1 = (ushort4*)&ph[512 + lane * 8];
  d1[0] = make_ushort4(lo[0], lo[1], lo[2], lo[3]);
  d1[1] = make_ushort4(lo[4], lo[5], lo[6], lo[7]);
}

// ---- PV GEMM: 64x192 tile, probs(split) @ vT(split) -> ctx split ----
__global__ __launch_bounds__(256) void pv_mm(
    const u16* __restrict__ pbase, const u16* __restrict__ vTh, const u16* __restrict__ vTl,
    u16* __restrict__ ch, u16* __restrict__ cl)
{
  __shared__ u16 lds[16384];
  const int z = blockIdx.y, b = z >> 2, hh = z & 3;
  const int bm = blockIdx.x * 64;
  const u16* ah_g = pbase + (size_t)z * SEQ * 1024 + (size_t)bm * 1024;
  const u16* al_g = ah_g + 512;
  const u16* bh_g = vTh + (size_t)b * HID * SEQ + (size_t)(hh * 192) * SEQ;
  const u16* bl_g = vTl + (size_t)b * HID * SEQ + (size_t)(hh * 192) * SEQ;
  const int tid = threadIdx.x, w = tid >> 6, ln = tid & 63;
  const int srow = ln >> 2;
  const int csw  = ((ln & 3) - (ln >> 3)) & 3;
  const int schunk = csw * 8;
  const int ml = ln & 15, quad = ln >> 4;
  const int fo2 = (((ln >> 4) + ((ln >> 1) & 3)) & 3) * 8;
  f4v acc[12];
#pragma unroll
  for (int j = 0; j < 12; ++j) acc[j] = (f4v)0.f;

  for (int ks = 0; ks < 16; ++ks) {
    const int k0 = ks * 32;
#pragma unroll
    for (int s = 0; s < 8; ++s) {
      const int p = w * 8 + s;
      const u16* g; u16* l;
      if (p < 4)       { g = ah_g + (size_t)(p * 16 + srow) * 1024 + k0 + schunk; l = lds + p * 512; }
      else if (p < 8)  { const int t = p - 4;  g = al_g + (size_t)(t * 16 + srow) * 1024 + k0 + schunk; l = lds + 2048 + t * 512; }
      else if (p < 20) { const int t = p - 8;  g = bh_g + (size_t)(t * 16 + srow) * 512 + k0 + schunk; l = lds + 4096 + t * 512; }
      else             { const int t = p - 20; g = bl_g + (size_t)(t * 16 + srow) * 512 + k0 + schunk; l = lds + 10240 + t * 512; }
      gl2lds16(g, l);
    }
    __syncthreads();
    const int ra = (w * 16 + ml) * 32 + fo2;
    const s8v a_h = *(const s8v*)&lds[ra];
    const s8v a_l = *(const s8v*)&lds[2048 + ra];
    s8v bh[12], bl[12];
#pragma unroll
    for (int j = 0; j < 12; ++j) {
      const int rb = (j * 16 + ml) * 32 + fo2;
      bh[j] = *(const s8v*)&lds[4096 + rb];
      bl[j] = *(const s8v*)&lds[10240 + rb];
    }
#pragma unroll
    for (int j = 0; j < 12; ++j)
      acc[j] = __builtin_amdgcn_mfma_f32_16x16x32_bf16(a_h, bh[j], acc[j], 0, 0, 0);
#pragma unroll
    for (int j = 0; j < 12; ++j)
      acc[j] = __builtin_amdgcn_mfma_f32_16x16x32_bf16(a_h, bl[j], acc[j], 0, 0, 0);
#pragma unroll
    for (int j = 0; j < 12; ++j)
      acc[j] = __builtin_amdgcn_mfma_f32_16x16x32_bf16(a_l, bh[j], acc[j], 0, 0, 0);
    __syncthreads();
  }
#pragma unroll
  for (int j = 0; j < 12; ++j) {
    const int gcol = hh * 192 + j * 16 + ml;
#pragma unroll
    for (int r = 0; r < 4; ++r) {
      const int m = bm + w * 16 + quad * 4 + r;
      const float v = acc[j][r];
      const size_t idx = (size_t)(b * SEQ + m) * HID + gcol;
      const u16 hi = f2bf(v);
      ch[idx] = hi;
      cl[idx] = f2bf(v - bf2f(hi));
    }
  }
}

// ---- projection GEMM + bias + residual -> h fp32 ----
__global__ __launch_bounds__(256) void proj_mm(
    const u16* __restrict__ ch, const u16* __restrict__ cl,
    const u16* __restrict__ WTh, const u16* __restrict__ WTl,
    const float* __restrict__ bo, const float* __restrict__ x, float* __restrict__ h)
{
  __shared__ u16 lds[16384];
  const int bm = blockIdx.y * 128, bn = blockIdx.x * 128;
  const size_t wtoff = (size_t)3 * HID * HID + (size_t)bn * HID;
  f4v acc[4][4];
#pragma unroll
  for (int i = 0; i < 4; ++i)
#pragma unroll
    for (int j = 0; j < 4; ++j) acc[i][j] = (f4v)0.f;
  mm_core128<24>(ch + (size_t)bm * HID, cl + (size_t)bm * HID, HID,
                 WTh + wtoff, WTl + wtoff, HID, lds, acc);
  const int tid = threadIdx.x, w = tid >> 6, ln = tid & 63;
  const int ml = ln & 15, quad = ln >> 4;
  const int wr = (w >> 1) * 64, wc = (w & 1) * 64;
#pragma unroll
  for (int i = 0; i < 4; ++i)
#pragma unroll
    for (int j = 0; j < 4; ++j) {
      const int gcol = bn + wc + j * 16 + ml;
      const float bv_ = bo[gcol];
#pragma unroll
      for (int r = 0; r < 4; ++r) {
        const int grow = bm + wr + i * 16 + quad * 4 + r;
        const size_t idx = (size_t)grow * HID + gcol;
        h[idx] = acc[i][j][r] + bv_ + x[idx];
      }
    }
}

// ---- LayerNorm + 9-label classifier ----
__global__ __launch_bounds__(256) void ln_logits_kernel(
    const float* __restrict__ h, const float* __restrict__ g,
    const float* __restrict__ bta, const float* __restrict__ Ws,
    const float* __restrict__ bsv, float* __restrict__ span)
{
  const int row = blockIdx.x;
  const int tid = threadIdx.x;
  const float* hr = h + (size_t)row * HID;
  const float x0 = hr[tid], x1 = hr[tid + 256], x2 = hr[tid + 512];
  float s = x0 + x1 + x2;
  float sq = x0 * x0 + x1 * x1 + x2 * x2;
#pragma unroll
  for (int o = 32; o > 0; o >>= 1) { s += __shfl_down(s, o, 64); sq += __shfl_down(sq, o, 64); }
  __shared__ float red[8];
  __shared__ float smu, srs;
  const int wid = tid >> 6, lid = tid & 63;
  if (lid == 0) { red[wid] = s; red[4 + wid] = sq; }
  __syncthreads();
  if (tid == 0) {
    const float ts = red[0] + red[1] + red[2] + red[3];
    const float tq = red[4] + red[5] + red[6] + red[7];
    const float mu = ts / 768.0f;
    const float var = tq / 768.0f - mu * mu;
    smu = mu; srs = rsqrtf(var + 1e-5f);
  }
  __syncthreads();
  const float mu = smu, rs = srs;
  const float n0 = (x0 - mu) * rs * g[tid] + bta[tid];
  const float n1 = (x1 - mu) * rs * g[tid + 256] + bta[tid + 256];
  const float n2 = (x2 - mu) * rs * g[tid + 512] + bta[tid + 512];
  float pl[9];
#pragma unroll
  for (int l = 0; l < 9; ++l)
    pl[l] = n0 * Ws[(size_t)tid * 9 + l]
          + n1 * Ws[(size_t)(tid + 256) * 9 + l]
          + n2 * Ws[(size_t)(tid + 512) * 9 + l];
#pragma unroll
  for (int l = 0; l < 9; ++l)
#pragma unroll
    for (int o = 32; o > 0; o >>= 1) pl[l] += __shfl_down(pl[l], o, 64);
  __shared__ float lred[4][9];
  if (lid == 0) {
#pragma unroll
    for (int l = 0; l < 9; ++l) lred[wid][l] = pl[l];
  }
  __syncthreads();
  if (tid < 9) {
    span[(size_t)row * 9 + tid] =
        lred[0][tid] + lred[1][tid] + lred[2][tid] + lred[3][tid] + bsv[tid];
  }
}

// ---- entity-bias bump ----
__global__ __launch_bounds__(256) void bump_kernel(
    const float* __restrict__ span, const float* __restrict__ eb, float* __restrict__ out)
{
  const int idx = blockIdx.x * 256 + threadIdx.x;
  if (idx >= ROWS) return;
  const int j = idx & (SEQ - 1);
  const float* sl = span + (size_t)idx * 9;
  float v[9];
#pragma unroll
  for (int l = 0; l < 9; ++l) v[l] = sl[l];
  if (j >= 1) {
    const float* sp = sl - 9;
    float m = sp[0]; int am = 0;
#pragma unroll
    for (int l = 1; l < 9; ++l) { const float t = sp[l]; if (t > m) { m = t; am = l; } }
    if (am == 1) v[2] += 2.0f * eb[2];
  }
#pragma unroll
  for (int l = 0; l < 9; ++l) out[(size_t)idx * 9 + l] = v[l];
}

extern "C" void kernel_launch(void* const* d_in, const int* in_sizes, int n_in,
                              void* d_out, int out_size, void* d_ws, size_t ws_size,
                              hipStream_t stream)
{
  (void)in_sizes; (void)n_in; (void)out_size; (void)ws_size;
  const float* x   = (const float*)d_in[0];
  const float* Wq  = (const float*)d_in[1];
  const float* bq  = (const float*)d_in[2];
  const float* Wk  = (const float*)d_in[3];
  const float* bk  = (const float*)d_in[4];
  const float* Wv  = (const float*)d_in[5];
  const float* bv  = (const float*)d_in[6];
  const float* Wo  = (const float*)d_in[7];
  const float* bo  = (const float*)d_in[8];
  const float* lng = (const float*)d_in[9];
  const float* lnb = (const float*)d_in[10];
  const float* Ws  = (const float*)d_in[11];
  const float* bs  = (const float*)d_in[12];
  const float* eb  = (const float*)d_in[13];
  float* out = (float*)d_out;

  char* ws = (char*)d_ws;
  u16* xh  = (u16*)(ws + 0);
  u16* xl  = (u16*)(ws + 12582912);
  u16* vTh = xh;
  u16* vTl = xl;
  u16* WTh = (u16*)(ws + 25165824);
  u16* WTl = (u16*)(ws + 29884416);
  u16* qh  = (u16*)(ws + 34603008);
  u16* ql  = (u16*)(ws + 47185920);
  u16* kh  = (u16*)(ws + 59768832);
  u16* kl  = (u16*)(ws + 72351744);
  float* scb = (float*)(ws + 84934656);
  float* spanb = (float*)(ws + 152043520);
  float* vtmp = scb;
  float* hb = scb;
  u16* ctxh = qh;
  u16* ctxl = ql;

  splitx<<<dim3(1572864 / 256), 256, 0, stream>>>(x, xh, xl);
  wsplit<<<dim3(24, 24, 4), 256, 0, stream>>>(Wq, Wk, Wv, Wo, WTh, WTl);
  qkv_fused<<<dim3(12, 64), 256, 0, stream>>>(xh, xl, WTh, WTl, bq, bk, bv,
                                              qh, ql, kh, kl, vtmp);
  vtrans<<<dim3(24, 16, 16), 256, 0, stream>>>(vtmp, vTh, vTl);
  scores_mm<<<dim3(4, 4, 64), 256, 0, stream>>>(qh, ql, kh, kl, scb);
  softmax_split<<<dim3(8192), 256, 0, stream>>>(scb);
  pv_mm<<<dim3(8, 64), 256, 0, stream>>>((const u16*)scb, vTh, vTl, ctxh, ctxl);
  proj_mm<<<dim3(6, 64), 256, 0, stream>>>(ctxh, ctxl, WTh, WTl, bo, x, hb);
  ln_logits_kernel<<<dim3(ROWS), 256, 0, stream>>>(hb, lng, lnb, Ws, bs, spanb);
  bump_kernel<<<dim3(ROWS / 256), 256, 0, stream>>>(spanb, eb, out);
}

// Round 5
// 419.055 us; speedup vs baseline: 1.0369x; 1.0369x over previous
//
#include <hip/hip_runtime.h>
#include <math.h>

#define SEQ 512
#define HID 768
#define NBATCH 16
#define ROWS 8192
#define INV_SQRT_D 0.07216878364870323f

typedef short s8v __attribute__((ext_vector_type(8)));
typedef float f4v __attribute__((ext_vector_type(4)));
typedef unsigned short u16;

// ---- bf16 helpers (RNE) ----
__device__ __forceinline__ u16 f2bf(float f) {
  unsigned u = __builtin_bit_cast(unsigned, f);
  unsigned r = u + 0x7FFFu + ((u >> 16) & 1u);
  return (u16)(r >> 16);
}
__device__ __forceinline__ float bf2f(u16 s) {
  unsigned u = ((unsigned)s) << 16;
  return __builtin_bit_cast(float, u);
}

// ---------------------------------------------------------------------------
// GEMM core v2: VGPR-prefetch double buffering (AITER-style staging path).
// Per K-step: ds_write prefetched regs -> barrier -> issue next global loads
// (latency hides under MFMA) -> swizzled ds_read frags -> 48 MFMA.
// LDS tile: 128 rows x 32 u16, logical (row,chunk) at row*32+((chunk+(row>>1))&3)*8
// -> conflict-free b128 reads; ds_writes are contiguous (conflict-free).
// ---------------------------------------------------------------------------
template <int KSTEPS>
__device__ __forceinline__ void mm_core128(
    const u16* __restrict__ Ah, const u16* __restrict__ Al, const int lda,
    const u16* __restrict__ Bh, const u16* __restrict__ Bl, const int ldb,
    u16* lds, f4v (&acc)[4][4])
{
  const int tid = threadIdx.x;
  const int w = tid >> 6, ln = tid & 63;
  const u16* src; int ld;
  if (w == 0)      { src = Ah; ld = lda; }
  else if (w == 1) { src = Al; ld = lda; }
  else if (w == 2) { src = Bh; ld = ldb; }
  else             { src = Bl; ld = ldb; }
  u16* myTile = lds + w * 4096;
  const int srow = ln >> 2;
  const int csw  = ((ln & 3) - (ln >> 3)) & 3;
  const int ml = ln & 15, quad = ln >> 4;
  const int fo2 = (((ln >> 4) + ((ln >> 1) & 3)) & 3) * 8;
  const int wr = (w >> 1) * 64, wc = (w & 1) * 64;

  const u16* gp[8];
  u16* lp[8];
#pragma unroll
  for (int t = 0; t < 8; ++t) {
    gp[t] = src + (size_t)(srow + t * 16) * ld + csw * 8;
    lp[t] = myTile + t * 512 + ln * 8;
  }
  s8v c[8];
#pragma unroll
  for (int t = 0; t < 8; ++t) c[t] = *(const s8v*)gp[t];

  for (int ks = 0; ks < KSTEPS; ++ks) {
    __syncthreads();                     // all waves done reading prev step
#pragma unroll
    for (int t = 0; t < 8; ++t) *(s8v*)lp[t] = c[t];
    __syncthreads();                     // staging visible
    if (ks + 1 < KSTEPS) {
      const int k0 = (ks + 1) * 32;
#pragma unroll
      for (int t = 0; t < 8; ++t) c[t] = *(const s8v*)(gp[t] + k0);
    }
    s8v ah[4], al[4], bh[4], bl[4];
#pragma unroll
    for (int i = 0; i < 4; ++i) {
      const int ra = (wr + i * 16 + ml) * 32 + fo2;
      ah[i] = *(const s8v*)&lds[ra];
      al[i] = *(const s8v*)&lds[4096 + ra];
      const int rb = (wc + i * 16 + ml) * 32 + fo2;
      bh[i] = *(const s8v*)&lds[8192 + rb];
      bl[i] = *(const s8v*)&lds[12288 + rb];
    }
#pragma unroll
    for (int i = 0; i < 4; ++i)
#pragma unroll
      for (int j = 0; j < 4; ++j)
        acc[i][j] = __builtin_amdgcn_mfma_f32_16x16x32_bf16(ah[i], bh[j], acc[i][j], 0, 0, 0);
#pragma unroll
    for (int i = 0; i < 4; ++i)
#pragma unroll
      for (int j = 0; j < 4; ++j)
        acc[i][j] = __builtin_amdgcn_mfma_f32_16x16x32_bf16(ah[i], bl[j], acc[i][j], 0, 0, 0);
#pragma unroll
    for (int i = 0; i < 4; ++i)
#pragma unroll
      for (int j = 0; j < 4; ++j)
        acc[i][j] = __builtin_amdgcn_mfma_f32_16x16x32_bf16(al[i], bh[j], acc[i][j], 0, 0, 0);
  }
}

// ---- prep: split x into hi/lo bf16 ----
__global__ __launch_bounds__(256) void splitx(const float* __restrict__ x,
                                              u16* __restrict__ xh, u16* __restrict__ xl)
{
  const int i = blockIdx.x * 256 + threadIdx.x;
  const float4 v = ((const float4*)x)[i];
  u16 h0 = f2bf(v.x), h1 = f2bf(v.y), h2 = f2bf(v.z), h3 = f2bf(v.w);
  ushort4 hv = make_ushort4(h0, h1, h2, h3);
  ushort4 lv = make_ushort4(f2bf(v.x - bf2f(h0)), f2bf(v.y - bf2f(h1)),
                            f2bf(v.z - bf2f(h2)), f2bf(v.w - bf2f(h3)));
  ((ushort4*)xh)[i] = hv;
  ((ushort4*)xl)[i] = lv;
}

// ---- prep: transpose + split weights: WT[z][n][k] = W_z[k][n] ----
__global__ __launch_bounds__(256) void wsplit(
    const float* __restrict__ Wq, const float* __restrict__ Wk,
    const float* __restrict__ Wv, const float* __restrict__ Wo,
    u16* __restrict__ WTh, u16* __restrict__ WTl)
{
  __shared__ float t[32][33];
  const int z = blockIdx.z;
  const float* W = (z == 0) ? Wq : (z == 1) ? Wk : (z == 2) ? Wv : Wo;
  const int n0 = blockIdx.x * 32, k0 = blockIdx.y * 32;
  const int tx = threadIdx.x & 31, ty = threadIdx.x >> 5;
#pragma unroll
  for (int i = 0; i < 4; ++i)
    t[ty + 8 * i][tx] = W[(size_t)(k0 + ty + 8 * i) * HID + n0 + tx];
  __syncthreads();
#pragma unroll
  for (int i = 0; i < 4; ++i) {
    const float v = t[tx][ty + 8 * i];
    const size_t idx = (size_t)z * HID * HID + (size_t)(n0 + ty + 8 * i) * HID + k0 + tx;
    const u16 hi = f2bf(v);
    WTh[idx] = hi;
    WTl[idx] = f2bf(v - bf2f(hi));
  }
}

// ---- QKV GEMM: z=0 -> q split, z=1 -> k split, z=2 -> v fp32 temp ----
__global__ __launch_bounds__(256, 2) void qkv_mm(
    const u16* __restrict__ xh, const u16* __restrict__ xl,
    const u16* __restrict__ WTh, const u16* __restrict__ WTl,
    const float* __restrict__ bq, const float* __restrict__ bk, const float* __restrict__ bv,
    u16* __restrict__ qh, u16* __restrict__ ql,
    u16* __restrict__ kh, u16* __restrict__ kl, float* __restrict__ vtmp)
{
  __shared__ u16 lds[16384];
  const int z = blockIdx.z;
  const int bm = blockIdx.y * 128, bn = blockIdx.x * 128;
  const size_t wtoff = (size_t)z * HID * HID + (size_t)bn * HID;
  f4v acc[4][4];
#pragma unroll
  for (int i = 0; i < 4; ++i)
#pragma unroll
    for (int j = 0; j < 4; ++j) acc[i][j] = (f4v)0.f;
  mm_core128<24>(xh + (size_t)bm * HID, xl + (size_t)bm * HID, HID,
                 WTh + wtoff, WTl + wtoff, HID, lds, acc);
  const int tid = threadIdx.x, w = tid >> 6, ln = tid & 63;
  const int ml = ln & 15, quad = ln >> 4;
  const int wr = (w >> 1) * 64, wc = (w & 1) * 64;
  const float* bias = (z == 0) ? bq : (z == 1) ? bk : bv;
#pragma unroll
  for (int i = 0; i < 4; ++i)
#pragma unroll
    for (int j = 0; j < 4; ++j) {
      const int gcol = bn + wc + j * 16 + ml;
      const float bv_ = bias[gcol];
#pragma unroll
      for (int r = 0; r < 4; ++r) {
        const int grow = bm + wr + i * 16 + quad * 4 + r;
        const float v = acc[i][j][r] + bv_;
        const size_t idx = (size_t)grow * HID + gcol;
        if (z == 2) {
          vtmp[idx] = v;
        } else {
          const u16 hi = f2bf(v);
          const u16 lo = f2bf(v - bf2f(hi));
          if (z == 0) { qh[idx] = hi; ql[idx] = lo; }
          else        { kh[idx] = hi; kl[idx] = lo; }
        }
      }
    }
}

// ---- prep: transpose + split v: vT[b][n][c] = vtmp[b][c][n] ----
__global__ __launch_bounds__(256) void vtrans(const float* __restrict__ vtmp,
                                              u16* __restrict__ vTh, u16* __restrict__ vTl)
{
  __shared__ float t[32][33];
  const int b = blockIdx.z, n0 = blockIdx.x * 32, c0 = blockIdx.y * 32;
  const int tx = threadIdx.x & 31, ty = threadIdx.x >> 5;
  const float* src = vtmp + (size_t)b * SEQ * HID;
#pragma unroll
  for (int i = 0; i < 4; ++i)
    t[ty + 8 * i][tx] = src[(size_t)(c0 + ty + 8 * i) * HID + n0 + tx];
  __syncthreads();
#pragma unroll
  for (int i = 0; i < 4; ++i) {
    const float v = t[tx][ty + 8 * i];
    const size_t idx = (size_t)b * HID * SEQ + (size_t)(n0 + ty + 8 * i) * SEQ + c0 + tx;
    const u16 hi = f2bf(v);
    vTh[idx] = hi;
    vTl[idx] = f2bf(v - bf2f(hi));
  }
}

// ---- scores GEMM + fused rel-bias/scale/dist-mask epilogue (fp32 out) ----
__global__ __launch_bounds__(256, 2) void scores_mm(
    const u16* __restrict__ qh, const u16* __restrict__ ql,
    const u16* __restrict__ kh, const u16* __restrict__ kl, float* __restrict__ sc)
{
  __shared__ u16 lds[16384];
  const int z = blockIdx.z, b = z >> 2, hh = z & 3;
  const int bm = blockIdx.y * 128, bn = blockIdx.x * 128;
  const size_t abase = (size_t)(b * SEQ + bm) * HID + hh * 192;
  const size_t bbase = (size_t)(b * SEQ + bn) * HID + hh * 192;
  f4v acc[4][4];
#pragma unroll
  for (int i = 0; i < 4; ++i)
#pragma unroll
    for (int j = 0; j < 4; ++j) acc[i][j] = (f4v)0.f;
  mm_core128<6>(qh + abase, ql + abase, HID, kh + bbase, kl + bbase, HID, lds, acc);
  const int tid = threadIdx.x, w = tid >> 6, ln = tid & 63;
  const int ml = ln & 15, quad = ln >> 4;
  const int wr = (w >> 1) * 64, wc = (w & 1) * 64;
  float* sch = sc + (size_t)z * SEQ * SEQ;
#pragma unroll
  for (int i = 0; i < 4; ++i)
#pragma unroll
    for (int j = 0; j < 4; ++j) {
      const int scol = bn + wc + j * 16 + ml;
#pragma unroll
      for (int r = 0; r < 4; ++r) {
        const int srow = bm + wr + i * 16 + quad * 4 + r;
        const float dist = fabsf((float)(srow - scol));
        const float rel = __expf(-0.1f * fminf(dist, 5.0f));
        sch[(size_t)srow * SEQ + scol] =
            (acc[i][j][r] + rel) * INV_SQRT_D - 0.1f * dist;
      }
    }
}

// ---- softmax in-place, writes probs hi/lo bf16 into the same row bytes ----
__global__ __launch_bounds__(256) void softmax_split(float* __restrict__ sc)
{
  const int blk = blockIdx.x;
  const int z = blk >> 7, rg = blk & 127;
  const int tid = threadIdx.x;
  const int rr = tid >> 6, lane = tid & 63;
  const int r = rg * 4 + rr;
  float* row = sc + (size_t)z * SEQ * SEQ + (size_t)r * SEQ;
  float4 v0 = *(const float4*)(row + lane * 8);
  float4 v1 = *(const float4*)(row + lane * 8 + 4);
  float mx = fmaxf(fmaxf(fmaxf(v0.x, v0.y), fmaxf(v0.z, v0.w)),
                   fmaxf(fmaxf(v1.x, v1.y), fmaxf(v1.z, v1.w)));
#pragma unroll
  for (int o = 32; o > 0; o >>= 1) mx = fmaxf(mx, __shfl_xor(mx, o, 64));
  v0.x = __expf(v0.x - mx); v0.y = __expf(v0.y - mx);
  v0.z = __expf(v0.z - mx); v0.w = __expf(v0.w - mx);
  v1.x = __expf(v1.x - mx); v1.y = __expf(v1.y - mx);
  v1.z = __expf(v1.z - mx); v1.w = __expf(v1.w - mx);
  float s = v0.x + v0.y + v0.z + v0.w + v1.x + v1.y + v1.z + v1.w;
#pragma unroll
  for (int o = 32; o > 0; o >>= 1) s += __shfl_xor(s, o, 64);
  const float inv = 1.0f / s;
  float p[8] = {v0.x * inv, v0.y * inv, v0.z * inv, v0.w * inv,
                v1.x * inv, v1.y * inv, v1.z * inv, v1.w * inv};
  u16 hi[8], lo[8];
#pragma unroll
  for (int t = 0; t < 8; ++t) {
    hi[t] = f2bf(p[t]);
    lo[t] = f2bf(p[t] - bf2f(hi[t]));
  }
  u16* ph = (u16*)row;
  ushort4* d0 = (ushort4*)&ph[lane * 8];
  d0[0] = make_ushort4(hi[0], hi[1], hi[2], hi[3]);
  d0[1] = make_ushort4(hi[4], hi[5], hi[6], hi[7]);
  ushort4* d1 = (ushort4*)&ph[512 + lane * 8];
  d1[0] = make_ushort4(lo[0], lo[1], lo[2], lo[3]);
  d1[1] = make_ushort4(lo[4], lo[5], lo[6], lo[7]);
}

// ---- PV GEMM: 64x192 tile, VGPR-prefetch staging ----
__global__ __launch_bounds__(256, 2) void pv_mm(
    const u16* __restrict__ pbase, const u16* __restrict__ vTh, const u16* __restrict__ vTl,
    u16* __restrict__ ch, u16* __restrict__ cl)
{
  __shared__ u16 lds[16384];   // Ah@0(2048) Al@2048 Bh@4096(6144) Bl@10240(6144)
  const int z = blockIdx.y, b = z >> 2, hh = z & 3;
  const int bm = blockIdx.x * 64;
  const u16* ah_g = pbase + (size_t)z * SEQ * 1024 + (size_t)bm * 1024;
  const u16* al_g = ah_g + 512;
  const u16* bh_g = vTh + (size_t)b * HID * SEQ + (size_t)(hh * 192) * SEQ;
  const u16* bl_g = vTl + (size_t)b * HID * SEQ + (size_t)(hh * 192) * SEQ;
  const int tid = threadIdx.x, w = tid >> 6, ln = tid & 63;
  const int srow = ln >> 2;
  const int csw  = ((ln & 3) - (ln >> 3)) & 3;
  const int schunk = csw * 8;
  const int ml = ln & 15, quad = ln >> 4;
  const int fo2 = (((ln >> 4) + ((ln >> 1) & 3)) & 3) * 8;

  const u16* gp[8];
  u16* lp[8];
#pragma unroll
  for (int s = 0; s < 8; ++s) {
    const int p = w * 8 + s;
    const u16* g; u16* l;
    if (p < 4)       { g = ah_g + (size_t)(p * 16 + srow) * 1024 + schunk; l = lds + p * 512; }
    else if (p < 8)  { const int t = p - 4;  g = al_g + (size_t)(t * 16 + srow) * 1024 + schunk; l = lds + 2048 + t * 512; }
    else if (p < 20) { const int t = p - 8;  g = bh_g + (size_t)(t * 16 + srow) * 512 + schunk; l = lds + 4096 + t * 512; }
    else             { const int t = p - 20; g = bl_g + (size_t)(t * 16 + srow) * 512 + schunk; l = lds + 10240 + t * 512; }
    gp[s] = g; lp[s] = l + ln * 8;
  }
  s8v c[8];
#pragma unroll
  for (int s = 0; s < 8; ++s) c[s] = *(const s8v*)gp[s];

  f4v acc[12];
#pragma unroll
  for (int j = 0; j < 12; ++j) acc[j] = (f4v)0.f;

  for (int ks = 0; ks < 16; ++ks) {
    __syncthreads();
#pragma unroll
    for (int s = 0; s < 8; ++s) *(s8v*)lp[s] = c[s];
    __syncthreads();
    if (ks + 1 < 16) {
      const int k0 = (ks + 1) * 32;
#pragma unroll
      for (int s = 0; s < 8; ++s) c[s] = *(const s8v*)(gp[s] + k0);
    }
    const int ra = (w * 16 + ml) * 32 + fo2;
    const s8v a_h = *(const s8v*)&lds[ra];
    const s8v a_l = *(const s8v*)&lds[2048 + ra];
    s8v bh[12], bl[12];
#pragma unroll
    for (int j = 0; j < 12; ++j) {
      const int rb = (j * 16 + ml) * 32 + fo2;
      bh[j] = *(const s8v*)&lds[4096 + rb];
      bl[j] = *(const s8v*)&lds[10240 + rb];
    }
#pragma unroll
    for (int j = 0; j < 12; ++j)
      acc[j] = __builtin_amdgcn_mfma_f32_16x16x32_bf16(a_h, bh[j], acc[j], 0, 0, 0);
#pragma unroll
    for (int j = 0; j < 12; ++j)
      acc[j] = __builtin_amdgcn_mfma_f32_16x16x32_bf16(a_h, bl[j], acc[j], 0, 0, 0);
#pragma unroll
    for (int j = 0; j < 12; ++j)
      acc[j] = __builtin_amdgcn_mfma_f32_16x16x32_bf16(a_l, bh[j], acc[j], 0, 0, 0);
  }
#pragma unroll
  for (int j = 0; j < 12; ++j) {
    const int gcol = hh * 192 + j * 16 + ml;
#pragma unroll
    for (int r = 0; r < 4; ++r) {
      const int m = bm + w * 16 + quad * 4 + r;
      const float v = acc[j][r];
      const size_t idx = (size_t)(b * SEQ + m) * HID + gcol;
      const u16 hi = f2bf(v);
      ch[idx] = hi;
      cl[idx] = f2bf(v - bf2f(hi));
    }
  }
}

// ---- projection GEMM + bias + residual -> h fp32 ----
__global__ __launch_bounds__(256, 2) void proj_mm(
    const u16* __restrict__ ch, const u16* __restrict__ cl,
    const u16* __restrict__ WTh, const u16* __restrict__ WTl,
    const float* __restrict__ bo, const float* __restrict__ x, float* __restrict__ h)
{
  __shared__ u16 lds[16384];
  const int bm = blockIdx.y * 128, bn = blockIdx.x * 128;
  const size_t wtoff = (size_t)3 * HID * HID + (size_t)bn * HID;
  f4v acc[4][4];
#pragma unroll
  for (int i = 0; i < 4; ++i)
#pragma unroll
    for (int j = 0; j < 4; ++j) acc[i][j] = (f4v)0.f;
  mm_core128<24>(ch + (size_t)bm * HID, cl + (size_t)bm * HID, HID,
                 WTh + wtoff, WTl + wtoff, HID, lds, acc);
  const int tid = threadIdx.x, w = tid >> 6, ln = tid & 63;
  const int ml = ln & 15, quad = ln >> 4;
  const int wr = (w >> 1) * 64, wc = (w & 1) * 64;
#pragma unroll
  for (int i = 0; i < 4; ++i)
#pragma unroll
    for (int j = 0; j < 4; ++j) {
      const int gcol = bn + wc + j * 16 + ml;
      const float bv_ = bo[gcol];
#pragma unroll
      for (int r = 0; r < 4; ++r) {
        const int grow = bm + wr + i * 16 + quad * 4 + r;
        const size_t idx = (size_t)grow * HID + gcol;
        h[idx] = acc[i][j][r] + bv_ + x[idx];
      }
    }
}

// ---- LayerNorm + 9-label classifier ----
__global__ __launch_bounds__(256) void ln_logits_kernel(
    const float* __restrict__ h, const float* __restrict__ g,
    const float* __restrict__ bta, const float* __restrict__ Ws,
    const float* __restrict__ bsv, float* __restrict__ span)
{
  const int row = blockIdx.x;
  const int tid = threadIdx.x;
  const float* hr = h + (size_t)row * HID;
  const float x0 = hr[tid], x1 = hr[tid + 256], x2 = hr[tid + 512];
  float s = x0 + x1 + x2;
  float sq = x0 * x0 + x1 * x1 + x2 * x2;
#pragma unroll
  for (int o = 32; o > 0; o >>= 1) { s += __shfl_down(s, o, 64); sq += __shfl_down(sq, o, 64); }
  __shared__ float red[8];
  __shared__ float smu, srs;
  const int wid = tid >> 6, lid = tid & 63;
  if (lid == 0) { red[wid] = s; red[4 + wid] = sq; }
  __syncthreads();
  if (tid == 0) {
    const float ts = red[0] + red[1] + red[2] + red[3];
    const float tq = red[4] + red[5] + red[6] + red[7];
    const float mu = ts / 768.0f;
    const float var = tq / 768.0f - mu * mu;
    smu = mu; srs = rsqrtf(var + 1e-5f);
  }
  __syncthreads();
  const float mu = smu, rs = srs;
  const float n0 = (x0 - mu) * rs * g[tid] + bta[tid];
  const float n1 = (x1 - mu) * rs * g[tid + 256] + bta[tid + 256];
  const float n2 = (x2 - mu) * rs * g[tid + 512] + bta[tid + 512];
  float pl[9];
#pragma unroll
  for (int l = 0; l < 9; ++l)
    pl[l] = n0 * Ws[(size_t)tid * 9 + l]
          + n1 * Ws[(size_t)(tid + 256) * 9 + l]
          + n2 * Ws[(size_t)(tid + 512) * 9 + l];
#pragma unroll
  for (int l = 0; l < 9; ++l)
#pragma unroll
    for (int o = 32; o > 0; o >>= 1) pl[l] += __shfl_down(pl[l], o, 64);
  __shared__ float lred[4][9];
  if (lid == 0) {
#pragma unroll
    for (int l = 0; l < 9; ++l) lred[wid][l] = pl[l];
  }
  __syncthreads();
  if (tid < 9) {
    span[(size_t)row * 9 + tid] =
        lred[0][tid] + lred[1][tid] + lred[2][tid] + lred[3][tid] + bsv[tid];
  }
}

// ---- entity-bias bump ----
__global__ __launch_bounds__(256) void bump_kernel(
    const float* __restrict__ span, const float* __restrict__ eb, float* __restrict__ out)
{
  const int idx = blockIdx.x * 256 + threadIdx.x;
  if (idx >= ROWS) return;
  const int j = idx & (SEQ - 1);
  const float* sl = span + (size_t)idx * 9;
  float v[9];
#pragma unroll
  for (int l = 0; l < 9; ++l) v[l] = sl[l];
  if (j >= 1) {
    const float* sp = sl - 9;
    float m = sp[0]; int am = 0;
#pragma unroll
    for (int l = 1; l < 9; ++l) { const float t = sp[l]; if (t > m) { m = t; am = l; } }
    if (am == 1) v[2] += 2.0f * eb[2];
  }
#pragma unroll
  for (int l = 0; l < 9; ++l) out[(size_t)idx * 9 + l] = v[l];
}

extern "C" void kernel_launch(void* const* d_in, const int* in_sizes, int n_in,
                              void* d_out, int out_size, void* d_ws, size_t ws_size,
                              hipStream_t stream)
{
  (void)in_sizes; (void)n_in; (void)out_size; (void)ws_size;
  const float* x   = (const float*)d_in[0];
  const float* Wq  = (const float*)d_in[1];
  const float* bq  = (const float*)d_in[2];
  const float* Wk  = (const float*)d_in[3];
  const float* bk  = (const float*)d_in[4];
  const float* Wv  = (const float*)d_in[5];
  const float* bv  = (const float*)d_in[6];
  const float* Wo  = (const float*)d_in[7];
  const float* bo  = (const float*)d_in[8];
  const float* lng = (const float*)d_in[9];
  const float* lnb = (const float*)d_in[10];
  const float* Ws  = (const float*)d_in[11];
  const float* bs  = (const float*)d_in[12];
  const float* eb  = (const float*)d_in[13];
  float* out = (float*)d_out;

  char* ws = (char*)d_ws;
  u16* xh  = (u16*)(ws + 0);
  u16* xl  = (u16*)(ws + 12582912);
  u16* vTh = xh;
  u16* vTl = xl;
  u16* WTh = (u16*)(ws + 25165824);
  u16* WTl = (u16*)(ws + 29884416);
  u16* qh  = (u16*)(ws + 34603008);
  u16* ql  = (u16*)(ws + 47185920);
  u16* kh  = (u16*)(ws + 59768832);
  u16* kl  = (u16*)(ws + 72351744);
  float* scb = (float*)(ws + 84934656);
  float* spanb = (float*)(ws + 152043520);
  float* vtmp = scb;
  float* hb = scb;
  u16* ctxh = qh;
  u16* ctxl = ql;

  splitx<<<dim3(1572864 / 256), 256, 0, stream>>>(x, xh, xl);
  wsplit<<<dim3(24, 24, 4), 256, 0, stream>>>(Wq, Wk, Wv, Wo, WTh, WTl);
  qkv_mm<<<dim3(6, 64, 3), 256, 0, stream>>>(xh, xl, WTh, WTl, bq, bk, bv,
                                             qh, ql, kh, kl, vtmp);
  vtrans<<<dim3(24, 16, 16), 256, 0, stream>>>(vtmp, vTh, vTl);
  scores_mm<<<dim3(4, 4, 64), 256, 0, stream>>>(qh, ql, kh, kl, scb);
  softmax_split<<<dim3(8192), 256, 0, stream>>>(scb);
  pv_mm<<<dim3(8, 64), 256, 0, stream>>>((const u16*)scb, vTh, vTl, ctxh, ctxl);
  proj_mm<<<dim3(6, 64), 256, 0, stream>>>(ctxh, ctxl, WTh, WTl, bo, x, hb);
  ln_logits_kernel<<<dim3(ROWS), 256, 0, stream>>>(hb, lng, lnb, Ws, bs, spanb);
  bump_kernel<<<dim3(ROWS / 256), 256, 0, stream>>>(spanb, eb, out);
}

// Round 6
// 391.330 us; speedup vs baseline: 1.1104x; 1.0708x over previous
//
#include <hip/hip_runtime.h>
#include <math.h>

#define SEQ 512
#define HID 768
#define NBATCH 16
#define ROWS 8192
#define INV_SQRT_D 0.07216878364870323f

typedef short s8v __attribute__((ext_vector_type(8)));
typedef float f4v __attribute__((ext_vector_type(4)));
typedef unsigned short u16;

// ---- bf16 helpers (RNE) ----
__device__ __forceinline__ u16 f2bf(float f) {
  unsigned u = __builtin_bit_cast(unsigned, f);
  unsigned r = u + 0x7FFFu + ((u >> 16) & 1u);
  return (u16)(r >> 16);
}
__device__ __forceinline__ float bf2f(u16 s) {
  unsigned u = ((unsigned)s) << 16;
  return __builtin_bit_cast(float, u);
}

// ---------------------------------------------------------------------------
// GEMM core: VGPR-prefetch double buffering. Per K-step: ds_write prefetched
// regs -> barrier -> issue next global loads -> swizzled ds_read frags -> 48 MFMA.
// LDS tile: 128 rows x 32 u16, logical (row,chunk) at row*32+((chunk+(row>>1))&3)*8
// -> conflict-free b128 reads; ds_writes contiguous (conflict-free).
// ---------------------------------------------------------------------------
template <int KSTEPS>
__device__ __forceinline__ void mm_core128(
    const u16* __restrict__ Ah, const u16* __restrict__ Al, const int lda,
    const u16* __restrict__ Bh, const u16* __restrict__ Bl, const int ldb,
    u16* lds, f4v (&acc)[4][4])
{
  const int tid = threadIdx.x;
  const int w = tid >> 6, ln = tid & 63;
  const u16* src; int ld;
  if (w == 0)      { src = Ah; ld = lda; }
  else if (w == 1) { src = Al; ld = lda; }
  else if (w == 2) { src = Bh; ld = ldb; }
  else             { src = Bl; ld = ldb; }
  u16* myTile = lds + w * 4096;
  const int srow = ln >> 2;
  const int csw  = ((ln & 3) - (ln >> 3)) & 3;
  const int ml = ln & 15, quad = ln >> 4;
  const int fo2 = (((ln >> 4) + ((ln >> 1) & 3)) & 3) * 8;
  const int wr = (w >> 1) * 64, wc = (w & 1) * 64;

  const u16* gp[8];
  u16* lp[8];
#pragma unroll
  for (int t = 0; t < 8; ++t) {
    gp[t] = src + (size_t)(srow + t * 16) * ld + csw * 8;
    lp[t] = myTile + t * 512 + ln * 8;
  }
  s8v c[8];
#pragma unroll
  for (int t = 0; t < 8; ++t) c[t] = *(const s8v*)gp[t];

  for (int ks = 0; ks < KSTEPS; ++ks) {
    __syncthreads();
#pragma unroll
    for (int t = 0; t < 8; ++t) *(s8v*)lp[t] = c[t];
    __syncthreads();
    if (ks + 1 < KSTEPS) {
      const int k0 = (ks + 1) * 32;
#pragma unroll
      for (int t = 0; t < 8; ++t) c[t] = *(const s8v*)(gp[t] + k0);
    }
    s8v ah[4], al[4], bh[4], bl[4];
#pragma unroll
    for (int i = 0; i < 4; ++i) {
      const int ra = (wr + i * 16 + ml) * 32 + fo2;
      ah[i] = *(const s8v*)&lds[ra];
      al[i] = *(const s8v*)&lds[4096 + ra];
      const int rb = (wc + i * 16 + ml) * 32 + fo2;
      bh[i] = *(const s8v*)&lds[8192 + rb];
      bl[i] = *(const s8v*)&lds[12288 + rb];
    }
#pragma unroll
    for (int i = 0; i < 4; ++i)
#pragma unroll
      for (int j = 0; j < 4; ++j)
        acc[i][j] = __builtin_amdgcn_mfma_f32_16x16x32_bf16(ah[i], bh[j], acc[i][j], 0, 0, 0);
#pragma unroll
    for (int i = 0; i < 4; ++i)
#pragma unroll
      for (int j = 0; j < 4; ++j)
        acc[i][j] = __builtin_amdgcn_mfma_f32_16x16x32_bf16(ah[i], bl[j], acc[i][j], 0, 0, 0);
#pragma unroll
    for (int i = 0; i < 4; ++i)
#pragma unroll
      for (int j = 0; j < 4; ++j)
        acc[i][j] = __builtin_amdgcn_mfma_f32_16x16x32_bf16(al[i], bh[j], acc[i][j], 0, 0, 0);
  }
}

// ---- prep: split x into hi/lo bf16 ----
__global__ __launch_bounds__(256) void splitx(const float* __restrict__ x,
                                              u16* __restrict__ xh, u16* __restrict__ xl)
{
  const int i = blockIdx.x * 256 + threadIdx.x;
  const float4 v = ((const float4*)x)[i];
  u16 h0 = f2bf(v.x), h1 = f2bf(v.y), h2 = f2bf(v.z), h3 = f2bf(v.w);
  ushort4 hv = make_ushort4(h0, h1, h2, h3);
  ushort4 lv = make_ushort4(f2bf(v.x - bf2f(h0)), f2bf(v.y - bf2f(h1)),
                            f2bf(v.z - bf2f(h2)), f2bf(v.w - bf2f(h3)));
  ((ushort4*)xh)[i] = hv;
  ((ushort4*)xl)[i] = lv;
}

// ---- prep: transpose + split weights: WT[z][n][k] = W_z[k][n] ----
__global__ __launch_bounds__(256) void wsplit(
    const float* __restrict__ Wq, const float* __restrict__ Wk,
    const float* __restrict__ Wv, const float* __restrict__ Wo,
    u16* __restrict__ WTh, u16* __restrict__ WTl)
{
  __shared__ float t[32][33];
  const int z = blockIdx.z;
  const float* W = (z == 0) ? Wq : (z == 1) ? Wk : (z == 2) ? Wv : Wo;
  const int n0 = blockIdx.x * 32, k0 = blockIdx.y * 32;
  const int tx = threadIdx.x & 31, ty = threadIdx.x >> 5;
#pragma unroll
  for (int i = 0; i < 4; ++i)
    t[ty + 8 * i][tx] = W[(size_t)(k0 + ty + 8 * i) * HID + n0 + tx];
  __syncthreads();
#pragma unroll
  for (int i = 0; i < 4; ++i) {
    const float v = t[tx][ty + 8 * i];
    const size_t idx = (size_t)z * HID * HID + (size_t)(n0 + ty + 8 * i) * HID + k0 + tx;
    const u16 hi = f2bf(v);
    WTh[idx] = hi;
    WTl[idx] = f2bf(v - bf2f(hi));
  }
}

// ---- QKV GEMM, XCD-swizzled 1D grid (1152 blocks) ----
// id&7 = XCD; per XCD: x (N-tile) fastest, then panel yl, then z. A-panel
// (8 per XCD, 3.2MB) stays L2-resident; W streams via L3.
__global__ __launch_bounds__(256, 3) void qkv_mm(
    const u16* __restrict__ xh, const u16* __restrict__ xl,
    const u16* __restrict__ WTh, const u16* __restrict__ WTl,
    const float* __restrict__ bq, const float* __restrict__ bk, const float* __restrict__ bv,
    u16* __restrict__ qh, u16* __restrict__ ql,
    u16* __restrict__ kh, u16* __restrict__ kl, float* __restrict__ vtmp)
{
  __shared__ u16 lds[16384];
  const int id = blockIdx.x;
  const int xcd = id & 7;
  const int s = id >> 3;            // 0..143
  const int bx = s % 6;
  const int yl = (s / 6) & 7;
  const int z  = s / 48;
  const int bm = (yl * 8 + xcd) * 128;
  const int bn = bx * 128;
  const size_t wtoff = (size_t)z * HID * HID + (size_t)bn * HID;
  f4v acc[4][4];
#pragma unroll
  for (int i = 0; i < 4; ++i)
#pragma unroll
    for (int j = 0; j < 4; ++j) acc[i][j] = (f4v)0.f;
  mm_core128<24>(xh + (size_t)bm * HID, xl + (size_t)bm * HID, HID,
                 WTh + wtoff, WTl + wtoff, HID, lds, acc);
  const int tid = threadIdx.x, w = tid >> 6, ln = tid & 63;
  const int ml = ln & 15, quad = ln >> 4;
  const int wr = (w >> 1) * 64, wc = (w & 1) * 64;
  const float* bias = (z == 0) ? bq : (z == 1) ? bk : bv;
#pragma unroll
  for (int i = 0; i < 4; ++i)
#pragma unroll
    for (int j = 0; j < 4; ++j) {
      const int gcol = bn + wc + j * 16 + ml;
      const float bv_ = bias[gcol];
#pragma unroll
      for (int r = 0; r < 4; ++r) {
        const int grow = bm + wr + i * 16 + quad * 4 + r;
        const float v = acc[i][j][r] + bv_;
        const size_t idx = (size_t)grow * HID + gcol;
        if (z == 2) {
          vtmp[idx] = v;
        } else {
          const u16 hi = f2bf(v);
          const u16 lo = f2bf(v - bf2f(hi));
          if (z == 0) { qh[idx] = hi; ql[idx] = lo; }
          else        { kh[idx] = hi; kl[idx] = lo; }
        }
      }
    }
}

// ---- prep: transpose + split v: vT[b][n][c] = vtmp[b][c][n] ----
__global__ __launch_bounds__(256) void vtrans(const float* __restrict__ vtmp,
                                              u16* __restrict__ vTh, u16* __restrict__ vTl)
{
  __shared__ float t[32][33];
  const int b = blockIdx.z, n0 = blockIdx.x * 32, c0 = blockIdx.y * 32;
  const int tx = threadIdx.x & 31, ty = threadIdx.x >> 5;
  const float* src = vtmp + (size_t)b * SEQ * HID;
#pragma unroll
  for (int i = 0; i < 4; ++i)
    t[ty + 8 * i][tx] = src[(size_t)(c0 + ty + 8 * i) * HID + n0 + tx];
  __syncthreads();
#pragma unroll
  for (int i = 0; i < 4; ++i) {
    const float v = t[tx][ty + 8 * i];
    const size_t idx = (size_t)b * HID * SEQ + (size_t)(n0 + ty + 8 * i) * SEQ + c0 + tx;
    const u16 hi = f2bf(v);
    vTh[idx] = hi;
    vTl[idx] = f2bf(v - bf2f(hi));
  }
}

// ---- scores GEMM + fused rel-bias/scale/dist-mask epilogue (fp32 out) ----
__global__ __launch_bounds__(256, 3) void scores_mm(
    const u16* __restrict__ qh, const u16* __restrict__ ql,
    const u16* __restrict__ kh, const u16* __restrict__ kl, float* __restrict__ sc)
{
  __shared__ u16 lds[16384];
  const int z = blockIdx.z, b = z >> 2, hh = z & 3;
  const int bm = blockIdx.y * 128, bn = blockIdx.x * 128;
  const size_t abase = (size_t)(b * SEQ + bm) * HID + hh * 192;
  const size_t bbase = (size_t)(b * SEQ + bn) * HID + hh * 192;
  f4v acc[4][4];
#pragma unroll
  for (int i = 0; i < 4; ++i)
#pragma unroll
    for (int j = 0; j < 4; ++j) acc[i][j] = (f4v)0.f;
  mm_core128<6>(qh + abase, ql + abase, HID, kh + bbase, kl + bbase, HID, lds, acc);
  const int tid = threadIdx.x, w = tid >> 6, ln = tid & 63;
  const int ml = ln & 15, quad = ln >> 4;
  const int wr = (w >> 1) * 64, wc = (w & 1) * 64;
  float* sch = sc + (size_t)z * SEQ * SEQ;
#pragma unroll
  for (int i = 0; i < 4; ++i)
#pragma unroll
    for (int j = 0; j < 4; ++j) {
      const int scol = bn + wc + j * 16 + ml;
#pragma unroll
      for (int r = 0; r < 4; ++r) {
        const int srow = bm + wr + i * 16 + quad * 4 + r;
        const float dist = fabsf((float)(srow - scol));
        const float rel = __expf(-0.1f * fminf(dist, 5.0f));
        sch[(size_t)srow * SEQ + scol] =
            (acc[i][j][r] + rel) * INV_SQRT_D - 0.1f * dist;
      }
    }
}

// ---- softmax in-place, writes probs hi/lo bf16 into the same row bytes ----
__global__ __launch_bounds__(256) void softmax_split(float* __restrict__ sc)
{
  const int blk = blockIdx.x;
  const int z = blk >> 7, rg = blk & 127;
  const int tid = threadIdx.x;
  const int rr = tid >> 6, lane = tid & 63;
  const int r = rg * 4 + rr;
  float* row = sc + (size_t)z * SEQ * SEQ + (size_t)r * SEQ;
  float4 v0 = *(const float4*)(row + lane * 8);
  float4 v1 = *(const float4*)(row + lane * 8 + 4);
  float mx = fmaxf(fmaxf(fmaxf(v0.x, v0.y), fmaxf(v0.z, v0.w)),
                   fmaxf(fmaxf(v1.x, v1.y), fmaxf(v1.z, v1.w)));
#pragma unroll
  for (int o = 32; o > 0; o >>= 1) mx = fmaxf(mx, __shfl_xor(mx, o, 64));
  v0.x = __expf(v0.x - mx); v0.y = __expf(v0.y - mx);
  v0.z = __expf(v0.z - mx); v0.w = __expf(v0.w - mx);
  v1.x = __expf(v1.x - mx); v1.y = __expf(v1.y - mx);
  v1.z = __expf(v1.z - mx); v1.w = __expf(v1.w - mx);
  float s = v0.x + v0.y + v0.z + v0.w + v1.x + v1.y + v1.z + v1.w;
#pragma unroll
  for (int o = 32; o > 0; o >>= 1) s += __shfl_xor(s, o, 64);
  const float inv = 1.0f / s;
  float p[8] = {v0.x * inv, v0.y * inv, v0.z * inv, v0.w * inv,
                v1.x * inv, v1.y * inv, v1.z * inv, v1.w * inv};
  u16 hi[8], lo[8];
#pragma unroll
  for (int t = 0; t < 8; ++t) {
    hi[t] = f2bf(p[t]);
    lo[t] = f2bf(p[t] - bf2f(hi[t]));
  }
  u16* ph = (u16*)row;
  ushort4* d0 = (ushort4*)&ph[lane * 8];
  d0[0] = make_ushort4(hi[0], hi[1], hi[2], hi[3]);
  d0[1] = make_ushort4(hi[4], hi[5], hi[6], hi[7]);
  ushort4* d1 = (ushort4*)&ph[512 + lane * 8];
  d1[0] = make_ushort4(lo[0], lo[1], lo[2], lo[3]);
  d1[1] = make_ushort4(lo[4], lo[5], lo[6], lo[7]);
}

// ---- PV GEMM: 64x192 tile, VGPR-prefetch staging ----
__global__ __launch_bounds__(256, 3) void pv_mm(
    const u16* __restrict__ pbase, const u16* __restrict__ vTh, const u16* __restrict__ vTl,
    u16* __restrict__ ch, u16* __restrict__ cl)
{
  __shared__ u16 lds[16384];
  const int z = blockIdx.y, b = z >> 2, hh = z & 3;
  const int bm = blockIdx.x * 64;
  const u16* ah_g = pbase + (size_t)z * SEQ * 1024 + (size_t)bm * 1024;
  const u16* al_g = ah_g + 512;
  const u16* bh_g = vTh + (size_t)b * HID * SEQ + (size_t)(hh * 192) * SEQ;
  const u16* bl_g = vTl + (size_t)b * HID * SEQ + (size_t)(hh * 192) * SEQ;
  const int tid = threadIdx.x, w = tid >> 6, ln = tid & 63;
  const int srow = ln >> 2;
  const int csw  = ((ln & 3) - (ln >> 3)) & 3;
  const int schunk = csw * 8;
  const int ml = ln & 15, quad = ln >> 4;
  const int fo2 = (((ln >> 4) + ((ln >> 1) & 3)) & 3) * 8;

  const u16* gp[8];
  u16* lp[8];
#pragma unroll
  for (int s = 0; s < 8; ++s) {
    const int p = w * 8 + s;
    const u16* g; u16* l;
    if (p < 4)       { g = ah_g + (size_t)(p * 16 + srow) * 1024 + schunk; l = lds + p * 512; }
    else if (p < 8)  { const int t = p - 4;  g = al_g + (size_t)(t * 16 + srow) * 1024 + schunk; l = lds + 2048 + t * 512; }
    else if (p < 20) { const int t = p - 8;  g = bh_g + (size_t)(t * 16 + srow) * 512 + schunk; l = lds + 4096 + t * 512; }
    else             { const int t = p - 20; g = bl_g + (size_t)(t * 16 + srow) * 512 + schunk; l = lds + 10240 + t * 512; }
    gp[s] = g; lp[s] = l + ln * 8;
  }
  s8v c[8];
#pragma unroll
  for (int s = 0; s < 8; ++s) c[s] = *(const s8v*)gp[s];

  f4v acc[12];
#pragma unroll
  for (int j = 0; j < 12; ++j) acc[j] = (f4v)0.f;

  for (int ks = 0; ks < 16; ++ks) {
    __syncthreads();
#pragma unroll
    for (int s = 0; s < 8; ++s) *(s8v*)lp[s] = c[s];
    __syncthreads();
    if (ks + 1 < 16) {
      const int k0 = (ks + 1) * 32;
#pragma unroll
      for (int s = 0; s < 8; ++s) c[s] = *(const s8v*)(gp[s] + k0);
    }
    const int ra = (w * 16 + ml) * 32 + fo2;
    const s8v a_h = *(const s8v*)&lds[ra];
    const s8v a_l = *(const s8v*)&lds[2048 + ra];
    s8v bh[12], bl[12];
#pragma unroll
    for (int j = 0; j < 12; ++j) {
      const int rb = (j * 16 + ml) * 32 + fo2;
      bh[j] = *(const s8v*)&lds[4096 + rb];
      bl[j] = *(const s8v*)&lds[10240 + rb];
    }
#pragma unroll
    for (int j = 0; j < 12; ++j)
      acc[j] = __builtin_amdgcn_mfma_f32_16x16x32_bf16(a_h, bh[j], acc[j], 0, 0, 0);
#pragma unroll
    for (int j = 0; j < 12; ++j)
      acc[j] = __builtin_amdgcn_mfma_f32_16x16x32_bf16(a_h, bl[j], acc[j], 0, 0, 0);
#pragma unroll
    for (int j = 0; j < 12; ++j)
      acc[j] = __builtin_amdgcn_mfma_f32_16x16x32_bf16(a_l, bh[j], acc[j], 0, 0, 0);
  }
#pragma unroll
  for (int j = 0; j < 12; ++j) {
    const int gcol = hh * 192 + j * 16 + ml;
#pragma unroll
    for (int r = 0; r < 4; ++r) {
      const int m = bm + w * 16 + quad * 4 + r;
      const float v = acc[j][r];
      const size_t idx = (size_t)(b * SEQ + m) * HID + gcol;
      const u16 hi = f2bf(v);
      ch[idx] = hi;
      cl[idx] = f2bf(v - bf2f(hi));
    }
  }
}

// ---- projection GEMM + bias + residual -> h fp32 (XCD-swizzled 1D grid) ----
__global__ __launch_bounds__(256, 3) void proj_mm(
    const u16* __restrict__ ch, const u16* __restrict__ cl,
    const u16* __restrict__ WTh, const u16* __restrict__ WTl,
    const float* __restrict__ bo, const float* __restrict__ x, float* __restrict__ h)
{
  __shared__ u16 lds[16384];
  const int id = blockIdx.x;
  const int xcd = id & 7;
  const int s = id >> 3;            // 0..47
  const int bx = s % 6;
  const int yl = s / 6;             // 0..7
  const int bm = (yl * 8 + xcd) * 128;
  const int bn = bx * 128;
  const size_t wtoff = (size_t)3 * HID * HID + (size_t)bn * HID;
  f4v acc[4][4];
#pragma unroll
  for (int i = 0; i < 4; ++i)
#pragma unroll
    for (int j = 0; j < 4; ++j) acc[i][j] = (f4v)0.f;
  mm_core128<24>(ch + (size_t)bm * HID, cl + (size_t)bm * HID, HID,
                 WTh + wtoff, WTl + wtoff, HID, lds, acc);
  const int tid = threadIdx.x, w = tid >> 6, ln = tid & 63;
  const int ml = ln & 15, quad = ln >> 4;
  const int wr = (w >> 1) * 64, wc = (w & 1) * 64;
#pragma unroll
  for (int i = 0; i < 4; ++i)
#pragma unroll
    for (int j = 0; j < 4; ++j) {
      const int gcol = bn + wc + j * 16 + ml;
      const float bv_ = bo[gcol];
#pragma unroll
      for (int r = 0; r < 4; ++r) {
        const int grow = bm + wr + i * 16 + quad * 4 + r;
        const size_t idx = (size_t)grow * HID + gcol;
        h[idx] = acc[i][j][r] + bv_ + x[idx];
      }
    }
}

// ---- LayerNorm + 9-label classifier ----
__global__ __launch_bounds__(256) void ln_logits_kernel(
    const float* __restrict__ h, const float* __restrict__ g,
    const float* __restrict__ bta, const float* __restrict__ Ws,
    const float* __restrict__ bsv, float* __restrict__ span)
{
  const int row = blockIdx.x;
  const int tid = threadIdx.x;
  const float* hr = h + (size_t)row * HID;
  const float x0 = hr[tid], x1 = hr[tid + 256], x2 = hr[tid + 512];
  float s = x0 + x1 + x2;
  float sq = x0 * x0 + x1 * x1 + x2 * x2;
#pragma unroll
  for (int o = 32; o > 0; o >>= 1) { s += __shfl_down(s, o, 64); sq += __shfl_down(sq, o, 64); }
  __shared__ float red[8];
  __shared__ float smu, srs;
  const int wid = tid >> 6, lid = tid & 63;
  if (lid == 0) { red[wid] = s; red[4 + wid] = sq; }
  __syncthreads();
  if (tid == 0) {
    const float ts = red[0] + red[1] + red[2] + red[3];
    const float tq = red[4] + red[5] + red[6] + red[7];
    const float mu = ts / 768.0f;
    const float var = tq / 768.0f - mu * mu;
    smu = mu; srs = rsqrtf(var + 1e-5f);
  }
  __syncthreads();
  const float mu = smu, rs = srs;
  const float n0 = (x0 - mu) * rs * g[tid] + bta[tid];
  const float n1 = (x1 - mu) * rs * g[tid + 256] + bta[tid + 256];
  const float n2 = (x2 - mu) * rs * g[tid + 512] + bta[tid + 512];
  float pl[9];
#pragma unroll
  for (int l = 0; l < 9; ++l)
    pl[l] = n0 * Ws[(size_t)tid * 9 + l]
          + n1 * Ws[(size_t)(tid + 256) * 9 + l]
          + n2 * Ws[(size_t)(tid + 512) * 9 + l];
#pragma unroll
  for (int l = 0; l < 9; ++l)
#pragma unroll
    for (int o = 32; o > 0; o >>= 1) pl[l] += __shfl_down(pl[l], o, 64);
  __shared__ float lred[4][9];
  if (lid == 0) {
#pragma unroll
    for (int l = 0; l < 9; ++l) lred[wid][l] = pl[l];
  }
  __syncthreads();
  if (tid < 9) {
    span[(size_t)row * 9 + tid] =
        lred[0][tid] + lred[1][tid] + lred[2][tid] + lred[3][tid] + bsv[tid];
  }
}

// ---- entity-bias bump ----
__global__ __launch_bounds__(256) void bump_kernel(
    const float* __restrict__ span, const float* __restrict__ eb, float* __restrict__ out)
{
  const int idx = blockIdx.x * 256 + threadIdx.x;
  if (idx >= ROWS) return;
  const int j = idx & (SEQ - 1);
  const float* sl = span + (size_t)idx * 9;
  float v[9];
#pragma unroll
  for (int l = 0; l < 9; ++l) v[l] = sl[l];
  if (j >= 1) {
    const float* sp = sl - 9;
    float m = sp[0]; int am = 0;
#pragma unroll
    for (int l = 1; l < 9; ++l) { const float t = sp[l]; if (t > m) { m = t; am = l; } }
    if (am == 1) v[2] += 2.0f * eb[2];
  }
#pragma unroll
  for (int l = 0; l < 9; ++l) out[(size_t)idx * 9 + l] = v[l];
}

extern "C" void kernel_launch(void* const* d_in, const int* in_sizes, int n_in,
                              void* d_out, int out_size, void* d_ws, size_t ws_size,
                              hipStream_t stream)
{
  (void)in_sizes; (void)n_in; (void)out_size; (void)ws_size;
  const float* x   = (const float*)d_in[0];
  const float* Wq  = (const float*)d_in[1];
  const float* bq  = (const float*)d_in[2];
  const float* Wk  = (const float*)d_in[3];
  const float* bk  = (const float*)d_in[4];
  const float* Wv  = (const float*)d_in[5];
  const float* bv  = (const float*)d_in[6];
  const float* Wo  = (const float*)d_in[7];
  const float* bo  = (const float*)d_in[8];
  const float* lng = (const float*)d_in[9];
  const float* lnb = (const float*)d_in[10];
  const float* Ws  = (const float*)d_in[11];
  const float* bs  = (const float*)d_in[12];
  const float* eb  = (const float*)d_in[13];
  float* out = (float*)d_out;

  char* ws = (char*)d_ws;
  u16* xh  = (u16*)(ws + 0);
  u16* xl  = (u16*)(ws + 12582912);
  u16* vTh = xh;
  u16* vTl = xl;
  u16* WTh = (u16*)(ws + 25165824);
  u16* WTl = (u16*)(ws + 29884416);
  u16* qh  = (u16*)(ws + 34603008);
  u16* ql  = (u16*)(ws + 47185920);
  u16* kh  = (u16*)(ws + 59768832);
  u16* kl  = (u16*)(ws + 72351744);
  float* scb = (float*)(ws + 84934656);
  float* spanb = (float*)(ws + 152043520);
  float* vtmp = scb;
  float* hb = scb;
  u16* ctxh = qh;
  u16* ctxl = ql;

  splitx<<<dim3(1572864 / 256), 256, 0, stream>>>(x, xh, xl);
  wsplit<<<dim3(24, 24, 4), 256, 0, stream>>>(Wq, Wk, Wv, Wo, WTh, WTl);
  qkv_mm<<<dim3(1152), 256, 0, stream>>>(xh, xl, WTh, WTl, bq, bk, bv,
                                         qh, ql, kh, kl, vtmp);
  vtrans<<<dim3(24, 16, 16), 256, 0, stream>>>(vtmp, vTh, vTl);
  scores_mm<<<dim3(4, 4, 64), 256, 0, stream>>>(qh, ql, kh, kl, scb);
  softmax_split<<<dim3(8192), 256, 0, stream>>>(scb);
  pv_mm<<<dim3(8, 64), 256, 0, stream>>>((const u16*)scb, vTh, vTl, ctxh, ctxl);
  proj_mm<<<dim3(384), 256, 0, stream>>>(ctxh, ctxl, WTh, WTl, bo, x, hb);
  ln_logits_kernel<<<dim3(ROWS), 256, 0, stream>>>(hb, lng, lnb, Ws, bs, spanb);
  bump_kernel<<<dim3(ROWS / 256), 256, 0, stream>>>(spanb, eb, out);
}